// Round 6
// baseline (6458.512 us; speedup 1.0000x reference)
//
#include <hip/hip_runtime.h>
#include <cfloat>
#include <math.h>

#define N 512
#define TG_ROUNDS 3
typedef unsigned long long u64_t;

__device__ __forceinline__ u64_t map_f64(double x) {
    u64_t b = (u64_t)__double_as_longlong(x);
    return b ^ ((b >> 63) ? 0xFFFFFFFFFFFFFFFFull : 0x8000000000000000ull);
}
__device__ __forceinline__ double unmap_f64(u64_t b) {
    b ^= ((b >> 63) ? 0x8000000000000000ull : 0xFFFFFFFFFFFFFFFFull);
    return __longlong_as_double((long long)b);
}

// wave64 u64 min-reduce via DPP (VALU pipe). Valid result in lane 63.
__device__ __forceinline__ u64_t wave_min_key(u64_t key) {
    unsigned hi = (unsigned)(key >> 32), lo = (unsigned)key;
#define MIN_STAGE(CTRL)                                                        \
    {                                                                          \
        unsigned oh = (unsigned)__builtin_amdgcn_update_dpp((int)hi, (int)hi,  \
                                                            CTRL, 0xF, 0xF, false); \
        unsigned ol = (unsigned)__builtin_amdgcn_update_dpp((int)lo, (int)lo,  \
                                                            CTRL, 0xF, 0xF, false); \
        const u64_t o = ((u64_t)oh << 32) | ol;                                \
        const u64_t c = ((u64_t)hi << 32) | lo;                                \
        if (o < c) { hi = oh; lo = ol; }                                       \
    }
    MIN_STAGE(0x111) MIN_STAGE(0x112) MIN_STAGE(0x114) MIN_STAGE(0x118)
    MIN_STAGE(0x142) MIN_STAGE(0x143)
#undef MIN_STAGE
    return ((u64_t)hi << 32) | lo;
}

// 512 threads / 8 waves. Thread t = column t+1 (and = row t+1 in scan phases).
// Warm start: column reduction + greedy + TG_ROUNDS x (parallel reduction
// transfer + parallel greedy augment) + sequential ARR. Then exact Dijkstra
// (round-5 core, unchanged). key = [45b value | 9b col-1 | 10b p[col]].
__global__ __launch_bounds__(512, 1) void tofu_solver(
    const float* __restrict__ dgm, const float* __restrict__ dgm_x,
    float* __restrict__ out)
{
#pragma clang fp contract(off)
    __shared__ double2 pt[N];           // dgm rows (f64)
    __shared__ double2 ptx[N];          // dgm_x cols (f64)
    __shared__ double  v_arr[N + 1];    // staged column duals (for row scans)
    __shared__ double  u_lds[N + 1];
    __shared__ int     p_lds[N + 1];    // p[j] = row matched to col j
    __shared__ int     way_lds[N + 1];
    __shared__ int     mcol[N + 1];     // mcol[i] = col matched to row i (warm start only)
    __shared__ int     claim[N + 1];
    __shared__ int     flist[4 * N + 32];
    __shared__ u64_t   dslot[3];
    __shared__ u64_t   aslot[2], bslot[2];
    __shared__ double  v1x;
    __shared__ double  red8[8];
    __shared__ int     nfree_s;

    const int tid  = threadIdx.x;       // 0..511
    const int col  = tid + 1;           // 1..512
    const int lane = tid & 63;
    const int wid  = tid >> 6;
    const float2* dgm2  = (const float2*)dgm;
    const float2* dgmx2 = (const float2*)dgm_x;

    // ---- stage ----
    {
        const float2 p2 = dgm2[tid];
        pt[tid] = make_double2((double)p2.x, (double)p2.y);
        const float2 q2 = dgmx2[tid];
        ptx[tid] = make_double2((double)q2.x, (double)q2.y);
    }
    const double xb = ptx[tid].x, xd = ptx[tid].y;  // own read, no race
    u_lds[col] = 0.0; p_lds[col] = 0; way_lds[col] = 0;
    mcol[col] = 0; claim[col] = 0x7fffffff;
    if (tid == 0) {
        u_lds[0] = 0.0; p_lds[0] = 0; way_lds[0] = 0; mcol[0] = 0;
        claim[0] = 0x7fffffff;
        dslot[0] = dslot[1] = dslot[2] = ~0ull;
        aslot[0] = aslot[1] = ~0ull; bslot[0] = bslot[1] = ~0ull;
    }
    __syncthreads();

    // ---- column reduction: v[j] = min_i c(i,j) (squared-dist argmin; sqrt monotone) ----
    double v_j; int amin;
    {
        double vsq = DBL_MAX; amin = 1;
        for (int i = 0; i < N; ++i) {
            const double2 rp = pt[i];               // broadcast
            const double db = rp.x - xb, dd = rp.y - xd;
            const double sq = db * db + dd * dd;
            if (sq < vsq) { vsq = sq; amin = i + 1; }
        }
        v_j = sqrt(vsq);
    }

    // ---- greedy: row r -> smallest col whose argmin is r (tight, u=0) ----
    atomicMin(&claim[amin], col);
    __syncthreads();
    if (claim[amin] == col) p_lds[col] = amin;
    __syncthreads();
    if (p_lds[col] != 0) mcol[p_lds[col]] = col;    // distinct rows: race-free
    v_arr[col] = v_j;
    __syncthreads();

    // ---- TG rounds: parallel reduction transfer + parallel greedy augment ----
    const double2 rp_own = pt[tid];                 // thread t's row = t+1
    for (int round = 0; round < TG_ROUNDS; ++round) {
        claim[col] = 0x7fffffff;                    // reset (ordered by prev barrier)
        const int row = col;
        const int mc  = mcol[row];
        double mu1 = DBL_MAX; int jmin = 1;
        for (int j = 0; j < N; ++j) {               // broadcast scans
            const double2 xp = ptx[j];
            const double vv = v_arr[j + 1];
            const double db = rp_own.x - xp.x, dd = rp_own.y - xp.y;
            const double cv = sqrt(db * db + dd * dd) - vv;
            if (mc) { if (j + 1 != mc && cv < mu1) mu1 = cv; }
            else    { if (cv < mu1) { mu1 = cv; jmin = j + 1; } }
        }
        __syncthreads();                            // scans done before v/claim writes
        if (mc) {
            // transfer: u[i]=mu; v[mc]=c(i,mc)-mu (<= old v by pre-round feasibility)
            const double2 xp = ptx[mc - 1];
            const double db = rp_own.x - xp.x, dd = rp_own.y - xp.y;
            u_lds[row] = mu1;
            v_arr[mc] = sqrt(db * db + dd * dd) - mu1;   // distinct mc: race-free
        } else if (p_lds[jmin] == 0) {
            atomicMin(&claim[jmin], row);           // free row claims free argmin col
        }
        __syncthreads();
        if (!mc && claim[jmin] == row) {            // unique winner; col still free
            p_lds[jmin] = row; mcol[row] = jmin; u_lds[row] = mu1;  // tight, feasible
        }
        __syncthreads();
    }
    v_j = v_arr[col];                               // reload post-transfer dual

    // ---- freelist of unmatched rows ----
    claim[col] = 0;
    __syncthreads();
    { const int r = p_lds[col]; if (r) claim[r] = 1; }
    __syncthreads();
    if (tid == 0) {
        int nf = 0;
        for (int r = 1; r <= N; ++r) if (!claim[r]) flist[nf++] = r;
        nfree_s = nf;
    }
    __syncthreads();

    // ---- sequential ARR (round-5 code, exactness-preserving, capped) ----
    {
        int head = 0, tail = nfree_s, q = 0;
        const int cap = 3 * tail + 16;
        int myp = p_lds[col];
        for (int step = 0; step < cap && head < tail; ++step) {
            const int i = flist[head++];
            const double2 rp = pt[i - 1];
            const double db = rp.x - xb, dd = rp.y - xd;
            const double val = sqrt(db * db + dd * dd) - v_j;
            const u64_t key = (map_f64(val) & ~0x7FFFFull)
                            | ((u64_t)(col - 1) << 10) | (u64_t)myp;
            u64_t kr = wave_min_key(key);
            if (lane == 63) atomicMin(&aslot[q], kr);
            __syncthreads();
            const u64_t k1 = aslot[q];
            const int j1    = (int)((k1 >> 10) & 511) + 1;
            const int k_old = (int)(k1 & 1023);
            if (col == j1) v1x = val;
            kr = wave_min_key((col == j1) ? ~0ull : key);
            if (lane == 63) atomicMin(&bslot[q], kr);
            __syncthreads();
            const double m2t = unmap_f64(bslot[q] & ~0x7FFFFull);
            const double ui  = fmax(m2t, v1x);      // <= exact 2nd-min, >= v1
            if (col == j1) { v_j -= (ui - val); myp = i; }
            if (tid == 0) {
                u_lds[i] = ui;
                p_lds[j1] = i;
                if (k_old) flist[tail] = k_old;
                aslot[q ^ 1] = ~0ull; bslot[q ^ 1] = ~0ull;
            }
            if (k_old) ++tail;
            q ^= 1;
            __syncthreads();
        }
    }

    // ---- rebuild freelist ----
    claim[col] = 0;
    __syncthreads();
    { const int r = p_lds[col]; if (r) claim[r] = 1; }
    __syncthreads();
    if (tid == 0) {
        int nf = 0;
        for (int r = 1; r <= N; ++r) if (!claim[r]) flist[nf++] = r;
        nfree_s = nf;
    }
    __syncthreads();
    const int nfree = nfree_s;

    // ---- exact Dijkstra phase (round-5 core) ----
    for (int kk = 0; kk < nfree; ++kk) {
        const int iroot = flist[kk];
        const int pcol  = p_lds[col];
        if (tid == 0) p_lds[0] = iroot;
        double minv = DBL_MAX, du = 0.0, du0 = 0.0;
        bool used = false;
        int juse = 0, i0 = iroot, par = 0;

        while (true) {
            if (col == juse) used = true;
            const double2 rp = pt[i0 - 1];          // broadcast
            const double u0 = u_lds[i0];            // row untouched this Dijkstra
            u64_t key = ~0ull;
            if (!used) {
                const double db = rp.x - xb, dd = rp.y - xd;
                const double c = sqrt(db * db + dd * dd);
                const double cur = (c - u0) - v_j;
                if (cur < minv) { minv = cur; way_lds[col] = juse; }
                key = (map_f64(minv) & ~0x7FFFFull)
                    | ((u64_t)(col - 1) << 10) | (u64_t)pcol;
            }
            key = wave_min_key(key);
            if (lane == 63) atomicMin(&dslot[par], key);
            __syncthreads();
            const u64_t k = dslot[par];
            if (tid == 0) dslot[(par + 2) % 3] = ~0ull;
            const double delta = unmap_f64(k & ~0x7FFFFull);
            if (used) { v_j -= delta; du += delta; }
            else        minv -= delta;
            if (tid == 0) du0 += delta;
            juse = (int)((k >> 10) & 511) + 1;
            i0   = (int)(k & 1023);
            if (i0 == 0) break;
            par = (par + 1) % 3;
        }

        if (used) u_lds[pcol] += du;                // distinct rows: race-free
        if (tid == 0) {
            u_lds[iroot] += du0;
            dslot[par] = ~0ull;
            int j = juse;
            while (j) { const int jn = way_lds[j]; p_lds[j] = p_lds[jn]; j = jn; }
        }
        __syncthreads();
    }

    // ---- loss = 0.5 * sum_j ||dgm[p[j]-1] - dgm_x[j-1]||^2 (f32 diffs like ref) ----
    const int r = p_lds[col] - 1;
    const float2 a = dgm2[r];
    const float2 b = dgmx2[tid];
    const float fb = a.x - b.x;
    const float fd = a.y - b.y;
    double acc = (double)fb * (double)fb + (double)fd * (double)fd;
    #pragma unroll
    for (int m = 32; m >= 1; m >>= 1) acc += __shfl_xor(acc, m, 64);
    if (lane == 0) red8[wid] = acc;
    __syncthreads();
    if (tid == 0) {
        double s = 0.0;
        #pragma unroll
        for (int w = 0; w < 8; ++w) s += red8[w];
        out[0] = (float)(0.5 * s);
    }
}

extern "C" void kernel_launch(void* const* d_in, const int* in_sizes, int n_in,
                              void* d_out, int out_size, void* d_ws, size_t ws_size,
                              hipStream_t stream) {
    const float* dgm   = (const float*)d_in[0];
    const float* dgm_x = (const float*)d_in[1];
    float* out = (float*)d_out;
    tofu_solver<<<1, 512, 0, stream>>>(dgm, dgm_x, out);
}